// Round 1
// baseline (1618.702 us; speedup 1.0000x reference)
//
#include <hip/hip_runtime.h>
#include <stdint.h>

// ---------------- constants ----------------
#define N_NODES 200000
#define DIM     128
#define N_EDGES 1024
#define NNZ_C   1600000
#define NT_TILES 6250        // N_NODES / 32 exactly

typedef __attribute__((ext_vector_type(8))) short short8;   // 8 bf16 (4 VGPRs)
typedef __attribute__((ext_vector_type(4))) float f32x4;

__device__ __forceinline__ float u2f(uint32_t u){ union{uint32_t u;float f;} x; x.u=u; return x.f; }
__device__ __forceinline__ uint32_t f2u(float f){ union{uint32_t u;float f;} x; x.f=f; return x.u; }
__device__ __forceinline__ unsigned short f2bf(float f){
  uint32_t u = f2u(f);
  u += 0x7fffu + ((u >> 16) & 1u);      // RNE
  return (unsigned short)(u >> 16);
}

// ---------------- weight prep (fp32 -> bf16, transposed to [col][k]) ----------------
__global__ void prep_tb_w(const float* __restrict__ W, short* __restrict__ Wt){
  int i = blockIdx.x*256 + threadIdx.x;
  if (i >= 5*384*128) return;
  int k   = i & 127;
  int col = (i >> 7) % 384;
  int s   = i / 49152;
  int j = col >> 7, n = col & 127;
  Wt[i] = (short)f2bf(W[((s*3 + j)*128 + k)*128 + n]);
}
__global__ void prep_hg_w(const float* __restrict__ W, short* __restrict__ Wt){
  int i = blockIdx.x*256 + threadIdx.x;
  if (i >= 2*128*128) return;
  int k = i & 127;
  int n = (i >> 7) & 127;
  int g = i >> 14;
  Wt[i] = (short)f2bf(W[(g*128 + k)*128 + n]);
}

// ---------------- CSR build ----------------
__global__ void count_kernel(const int* __restrict__ nidx, const int* __restrict__ eidx,
                             int* __restrict__ ncnt, int* __restrict__ ecnt){
  int i = blockIdx.x*256 + threadIdx.x;
  if (i < NNZ_C){
    atomicAdd(&ecnt[eidx[i]], 1);
    atomicAdd(&ncnt[nidx[i]], 1);
  }
}

__global__ void edge_scan_kernel(const int* __restrict__ ecnt, int* __restrict__ eoff, int* __restrict__ ecur){
  __shared__ int sc[1024];
  int t = threadIdx.x;
  int c = ecnt[t];
  sc[t] = c; __syncthreads();
  for (int off=1; off<1024; off<<=1){
    int v = (t >= off) ? sc[t-off] : 0;
    __syncthreads();
    sc[t] += v;
    __syncthreads();
  }
  int excl = sc[t] - c;
  eoff[t] = excl; ecur[t] = excl;
  if (t == 1023) eoff[1024] = sc[1023];
}

__global__ void nscanA(const int* __restrict__ ncnt, int* __restrict__ ntmp, int* __restrict__ bsum){
  __shared__ int sc[1024];
  int t = threadIdx.x, i = blockIdx.x*1024 + t;
  int c = (i < N_NODES) ? ncnt[i] : 0;
  sc[t] = c; __syncthreads();
  for (int off=1; off<1024; off<<=1){
    int v = (t >= off) ? sc[t-off] : 0;
    __syncthreads();
    sc[t] += v;
    __syncthreads();
  }
  if (i < N_NODES) ntmp[i] = sc[t];
  if (t == 1023) bsum[blockIdx.x] = sc[1023];
}
__global__ void nscanB(const int* __restrict__ bsum, int* __restrict__ bbase, int nb){
  __shared__ int sc[256];
  int t = threadIdx.x;
  int c = (t < nb) ? bsum[t] : 0;
  sc[t] = c; __syncthreads();
  for (int off=1; off<256; off<<=1){
    int v = (t >= off) ? sc[t-off] : 0;
    __syncthreads();
    sc[t] += v;
    __syncthreads();
  }
  bbase[t] = sc[t] - c;
}
__global__ void nscanC(const int* __restrict__ ntmp, const int* __restrict__ ncnt,
                       const int* __restrict__ bbase, int* __restrict__ noff, int* __restrict__ ncur){
  int t = threadIdx.x, i = blockIdx.x*1024 + t;
  if (i < N_NODES){
    int excl = bbase[blockIdx.x] + ntmp[i] - ncnt[i];
    noff[i] = excl; ncur[i] = excl;
  }
  if (i == 0) noff[N_NODES] = NNZ_C;
}

__global__ void fill_kernel(const int* __restrict__ nidx, const int* __restrict__ eidx,
                            int* __restrict__ ecur, int* __restrict__ ncur,
                            int* __restrict__ enodes, int* __restrict__ nedges){
  int i = blockIdx.x*256 + threadIdx.x;
  if (i < NNZ_C){
    int e = eidx[i], v = nidx[i];
    enodes[atomicAdd(&ecur[e], 1)] = v;
    nedges[atomicAdd(&ncur[v], 1)] = e;
  }
}

// ---------------- GEMM: [N,128] @ [128, CH*128], MFMA 16x16x32 bf16 ----------------
// Wave w owns cols j*128 + w*32 + {0..31} for each chunk j, so the three
// time-block branches (c1, sigmoid(c2), c3) combine in-register.
// A staged 32 rows/iter in LDS (pad 136 shorts: 68-dword stride, 16B-aligned b128 reads).
template<bool IN_F32, bool OUT_F32, int CH, bool ACT>
__global__ __launch_bounds__(256, 2) void gemm_kernel(
    const void* __restrict__ in, void* __restrict__ out,
    const short* __restrict__ Wt, const float* __restrict__ bias)
{
  __shared__ short Atile[32][136];
  const int tid  = threadIdx.x;
  const int lane = tid & 63;
  const int w    = tid >> 6;
  const int l15  = lane & 15;
  const int quad = lane >> 4;

  // B fragments: persistent in registers (L2-hot loads, once per block)
  short8 bfrag[CH][2][4];
  #pragma unroll
  for (int j = 0; j < CH; j++)
    #pragma unroll
    for (int nt = 0; nt < 2; nt++){
      const short* bp = Wt + (j*128 + w*32 + nt*16 + l15)*128 + quad*8;
      #pragma unroll
      for (int ks = 0; ks < 4; ks++)
        bfrag[j][nt][ks] = *(const short8*)(bp + ks*32);
    }

  float bv[ACT ? 3 : 1][2];
  if (ACT){
    #pragma unroll
    for (int j = 0; j < 3; j++)
      #pragma unroll
      for (int nt = 0; nt < 2; nt++)
        bv[j][nt] = bias[j*128 + w*32 + nt*16 + l15];
  }

  const int arow = tid >> 3;          // 0..31
  const int aseg = (tid & 7) * 2;     // 16B-chunk pair -> 32B contiguous / thread

  short8 pre0, pre1;
  auto loadA = [&](int t){
    int off = (t*32 + arow)*128 + aseg*8;
    if (IN_F32){
      const float* f = (const float*)in + off;
      f32x4 q0 = ((const f32x4*)f)[0];
      f32x4 q1 = ((const f32x4*)f)[1];
      f32x4 q2 = ((const f32x4*)f)[2];
      f32x4 q3 = ((const f32x4*)f)[3];
      short8 t0, t1;
      #pragma unroll
      for (int u = 0; u < 4; u++){
        t0[u]   = (short)f2bf(q0[u]);
        t0[u+4] = (short)f2bf(q1[u]);
        t1[u]   = (short)f2bf(q2[u]);
        t1[u+4] = (short)f2bf(q3[u]);
      }
      pre0 = t0; pre1 = t1;
    } else {
      const short* hp = (const short*)in + off;
      pre0 = *(const short8*)hp;
      pre1 = *(const short8*)(hp + 8);
    }
  };

  int t = blockIdx.x;
  loadA(t);                 // gridDim (1024) < NT_TILES always
  for (;;){
    __syncthreads();        // previous iter's ds_reads done
    *(short8*)&Atile[arow][aseg*8]     = pre0;
    *(short8*)&Atile[arow][aseg*8 + 8] = pre1;
    __syncthreads();
    int tn = t + gridDim.x;
    if (tn < NT_TILES) loadA(tn);     // next tile's global loads overlap compute

    const int base = t*32;
    #pragma unroll
    for (int rt = 0; rt < 2; rt++){
      short8 af[4];
      #pragma unroll
      for (int ks = 0; ks < 4; ks++)
        af[ks] = *(const short8*)&Atile[rt*16 + l15][ks*32 + quad*8];

      f32x4 acc[CH][2];
      #pragma unroll
      for (int j = 0; j < CH; j++)
        #pragma unroll
        for (int nt = 0; nt < 2; nt++){
          acc[j][nt] = (f32x4){0.f, 0.f, 0.f, 0.f};
          #pragma unroll
          for (int ks = 0; ks < 4; ks++)
            acc[j][nt] = __builtin_amdgcn_mfma_f32_16x16x32_bf16(
                af[ks], bfrag[j][nt][ks], acc[j][nt], 0, 0, 0);
        }

      #pragma unroll
      for (int nt = 0; nt < 2; nt++){
        int col = w*32 + nt*16 + l15;
        #pragma unroll
        for (int r = 0; r < 4; r++){
          int row = base + rt*16 + quad*4 + r;
          float v;
          if (ACT){
            float c2 = acc[1][nt][r] + bv[1][nt];
            float sg = 1.f / (1.f + __expf(-c2));
            v = acc[0][nt][r] + bv[0][nt] + sg + acc[2][nt][r] + bv[2][nt];
            v = fmaxf(v, 0.f);
          } else {
            v = acc[0][nt][r];
          }
          if (OUT_F32) ((float*)out)[row*128 + col] = v;
          else ((unsigned short*)out)[row*128 + col] = f2bf(v);
        }
      }
    }
    if (tn >= NT_TILES) break;
    t = tn;
  }
}

// ---------------- edge aggregation: m[e] = (1/|e|) * sum_{v in e} xp[v] ----------------
__global__ __launch_bounds__(256) void edge_sum_kernel(
    const unsigned short* __restrict__ xp, const int* __restrict__ eoff,
    const int* __restrict__ enodes, float* __restrict__ m)
{
  int e = blockIdx.x;
  int s = eoff[e], tend = eoff[e+1];
  int tid = threadIdx.x;
  int r8 = tid >> 5, ch = tid & 31;   // 8 rows in flight, 32 x 8B per row (coalesced 256B)
  float a0 = 0.f, a1 = 0.f, a2 = 0.f, a3 = 0.f;
  for (int i = s + r8; i < tend; i += 8){
    int node = enodes[i];
    uint2 raw = *(const uint2*)(xp + node*128 + ch*4);
    a0 += u2f(raw.x << 16);
    a1 += u2f(raw.x & 0xffff0000u);
    a2 += u2f(raw.y << 16);
    a3 += u2f(raw.y & 0xffff0000u);
  }
  __shared__ float red[8][132];
  red[r8][ch*4+0] = a0; red[r8][ch*4+1] = a1;
  red[r8][ch*4+2] = a2; red[r8][ch*4+3] = a3;
  __syncthreads();
  if (tid < 128){
    float sum = 0.f;
    #pragma unroll
    for (int r = 0; r < 8; r++) sum += red[r][tid];
    int cnt = tend - s;
    float be = cnt ? (1.f / (float)cnt) : 0.f;
    m[e*128 + tid] = sum * be;
  }
}

// ---------------- node aggregation: out[v] = (1/deg) * sum_{e ni v} m[e] + b ----------------
__global__ __launch_bounds__(256) void node_out_kernel(
    const float* __restrict__ m, const int* __restrict__ noff,
    const int* __restrict__ nedges, const float* __restrict__ hb,
    unsigned int* __restrict__ outp)
{
  int gw   = (blockIdx.x*256 + threadIdx.x) >> 6;   // one wave per node
  int lane = threadIdx.x & 63;
  int nw   = (gridDim.x*256) >> 6;
  float b0 = hb[lane*2], b1 = hb[lane*2+1];
  for (int v = gw; v < N_NODES; v += nw){
    int s = noff[v], e = noff[v+1];
    float a0 = 0.f, a1 = 0.f;
    for (int i = s; i < e; i++){
      int ed = nedges[i];
      float2 mm = *(const float2*)(m + ed*128 + lane*2);
      a0 += mm.x; a1 += mm.y;
    }
    float dn = (e > s) ? 1.f / (float)(e - s) : 0.f;
    a0 = a0*dn + b0;
    a1 = a1*dn + b1;
    outp[v*64 + lane] = ((uint32_t)f2bf(a1) << 16) | (uint32_t)f2bf(a0);
  }
}

// ---------------- host launch ----------------
extern "C" void kernel_launch(void* const* d_in, const int* in_sizes, int n_in,
                              void* d_out, int out_size, void* d_ws, size_t ws_size,
                              hipStream_t stream)
{
  (void)in_sizes; (void)n_in; (void)out_size; (void)ws_size;
  const float* x   = (const float*)d_in[0];
  const float* tbW = (const float*)d_in[1];
  const float* tbb = (const float*)d_in[2];
  const float* hgW = (const float*)d_in[3];
  const float* hgb = (const float*)d_in[4];
  const int* nidx  = (const int*)d_in[6];
  const int* eidx  = (const int*)d_in[7];
  float* out = (float*)d_out;

  char* p = (char*)d_ws;
  auto alloc = [&](size_t sz){ void* r = (void*)p; p += (sz + 255) & ~(size_t)255; return r; };
  unsigned short* hA = (unsigned short*)alloc((size_t)N_NODES*DIM*2);  // 51.2 MB
  unsigned short* hB = (unsigned short*)alloc((size_t)N_NODES*DIM*2);  // 51.2 MB
  float* m    = (float*)alloc((size_t)N_EDGES*DIM*4);                  // 512 KB
  short* WtTb = (short*)alloc((size_t)5*384*128*2);
  short* WtHg = (short*)alloc((size_t)2*128*128*2);
  int* ecnt = (int*)alloc(N_EDGES*4);
  int* eoff = (int*)alloc((N_EDGES+1)*4);
  int* ecur = (int*)alloc(N_EDGES*4);
  int* ncnt = (int*)alloc((size_t)N_NODES*4);
  int* ntmp = (int*)alloc((size_t)N_NODES*4);
  int* noff = (int*)alloc((size_t)(N_NODES+1)*4);
  int* ncur = (int*)alloc((size_t)N_NODES*4);
  int* bsum = (int*)alloc(256*4);
  int* bbase= (int*)alloc(256*4);
  int* enodes = (int*)alloc((size_t)NNZ_C*4);
  int* nedges = (int*)alloc((size_t)NNZ_C*4);

  hipMemsetAsync(ecnt, 0, N_EDGES*4, stream);
  hipMemsetAsync(ncnt, 0, (size_t)N_NODES*4, stream);

  prep_tb_w<<<960, 256, 0, stream>>>(tbW, WtTb);
  prep_hg_w<<<128, 256, 0, stream>>>(hgW, WtHg);

  count_kernel<<<6250, 256, 0, stream>>>(nidx, eidx, ncnt, ecnt);
  edge_scan_kernel<<<1, 1024, 0, stream>>>(ecnt, eoff, ecur);
  nscanA<<<196, 1024, 0, stream>>>(ncnt, ntmp, bsum);
  nscanB<<<1, 256, 0, stream>>>(bsum, bbase, 196);
  nscanC<<<196, 1024, 0, stream>>>(ntmp, ncnt, bbase, noff, ncur);
  fill_kernel<<<6250, 256, 0, stream>>>(nidx, eidx, ecur, ncur, enodes, nedges);

  // TB0: x (fp32) -> hA (bf16)
  gemm_kernel<true,  false, 3, true ><<<1024, 256, 0, stream>>>(x,  hA, WtTb, tbb);
  // conv0: xp = hA @ hgW0 -> hB; edge agg -> m; node agg (+b) -> hA
  gemm_kernel<false, false, 1, false><<<1024, 256, 0, stream>>>(hA, hB, WtHg, nullptr);
  edge_sum_kernel<<<N_EDGES, 256, 0, stream>>>(hB, eoff, enodes, m);
  node_out_kernel<<<2048, 256, 0, stream>>>(m, noff, nedges, hgb, (unsigned int*)hA);
  // TB1, TB2
  gemm_kernel<false, false, 3, true ><<<1024, 256, 0, stream>>>(hA, hB, WtTb + 1*49152, tbb + 1*384);
  gemm_kernel<false, false, 3, true ><<<1024, 256, 0, stream>>>(hB, hA, WtTb + 2*49152, tbb + 2*384);
  // conv1
  gemm_kernel<false, false, 1, false><<<1024, 256, 0, stream>>>(hA, hB, WtHg + 16384, nullptr);
  edge_sum_kernel<<<N_EDGES, 256, 0, stream>>>(hB, eoff, enodes, m);
  node_out_kernel<<<2048, 256, 0, stream>>>(m, noff, nedges, hgb + 128, (unsigned int*)hA);
  // TB3, TB4 (final -> fp32 d_out)
  gemm_kernel<false, false, 3, true ><<<1024, 256, 0, stream>>>(hA, hB, WtTb + 3*49152, tbb + 3*384);
  gemm_kernel<false, true,  3, true ><<<1024, 256, 0, stream>>>(hB, out, WtTb + 4*49152, tbb + 4*384);
}

// Round 2
// 990.694 us; speedup vs baseline: 1.6339x; 1.6339x over previous
//
#include <hip/hip_runtime.h>
#include <stdint.h>

// ---------------- constants ----------------
#define N_NODES 200000
#define DIM     128
#define N_EDGES 1024
#define NNZ_C   1600000
#define NT_TILES 6250        // N_NODES / 32 exactly

// CSR-build binning
#define NBLK   250           // histogram/scatter blocks
#define CHUNK  6400          // NNZ / NBLK
#define ITERS  25            // CHUNK / 256
#define NCB    196           // coarse node buckets of 1024 nodes (195*1024+320)

typedef __attribute__((ext_vector_type(8))) short short8;   // 8 bf16 (4 VGPRs)
typedef __attribute__((ext_vector_type(4))) float f32x4;

__device__ __forceinline__ float u2f(uint32_t u){ union{uint32_t u;float f;} x; x.u=u; return x.f; }
__device__ __forceinline__ uint32_t f2u(float f){ union{uint32_t u;float f;} x; x.f=f; return x.u; }
__device__ __forceinline__ unsigned short f2bf(float f){
  uint32_t u = f2u(f);
  u += 0x7fffu + ((u >> 16) & 1u);      // RNE
  return (unsigned short)(u >> 16);
}

// ---------------- weight prep (fp32 -> bf16, transposed to [col][k]) ----------------
__global__ void prep_tb_w(const float* __restrict__ W, short* __restrict__ Wt){
  int i = blockIdx.x*256 + threadIdx.x;
  if (i >= 5*384*128) return;
  int k   = i & 127;
  int col = (i >> 7) % 384;
  int s   = i / 49152;
  int j = col >> 7, n = col & 127;
  Wt[i] = (short)f2bf(W[((s*3 + j)*128 + k)*128 + n]);
}
__global__ void prep_hg_w(const float* __restrict__ W, short* __restrict__ Wt){
  int i = blockIdx.x*256 + threadIdx.x;
  if (i >= 2*128*128) return;
  int k = i & 127;
  int n = (i >> 7) & 127;
  int g = i >> 14;
  Wt[i] = (short)f2bf(W[(g*128 + k)*128 + n]);
}

// ---------------- CSR build: deterministic binned counting sort ----------------
// Pass 1: per-block LDS histograms (1024 edges + 196 coarse node buckets)
__global__ __launch_bounds__(256) void hist_kernel(
    const int* __restrict__ nidx, const int* __restrict__ eidx,
    int* __restrict__ ebh, int* __restrict__ nbh)
{
  __shared__ int eh[N_EDGES];
  __shared__ int nh[NCB];
  int tid = threadIdx.x, blk = blockIdx.x;
  #pragma unroll
  for (int l = tid; l < N_EDGES; l += 256) eh[l] = 0;
  for (int l = tid; l < NCB; l += 256) nh[l] = 0;
  __syncthreads();
  int base = blk*CHUNK;
  for (int it = 0; it < ITERS; it++){
    int i = base + it*256 + tid;
    atomicAdd(&eh[eidx[i]], 1);
    atomicAdd(&nh[nidx[i] >> 10], 1);
  }
  __syncthreads();
  for (int l = tid; l < N_EDGES; l += 256) ebh[blk*N_EDGES + l] = eh[l];
  for (int l = tid; l < NCB; l += 256) nbh[blk*NCB + l] = nh[l];
}

// Scan edge histograms -> eoff[1025] + per-block bases (in place in ebh)
__global__ __launch_bounds__(1024) void escan_kernel(
    int* __restrict__ ebh, int* __restrict__ eoff)
{
  __shared__ int sc[1024];
  int e = threadIdx.x;
  int total = 0;
  for (int b = 0; b < NBLK; b++){
    int idx = b*N_EDGES + e;
    int t = ebh[idx];
    ebh[idx] = total;
    total += t;
  }
  sc[e] = total; __syncthreads();
  for (int off=1; off<1024; off<<=1){
    int v = (e >= off) ? sc[e-off] : 0;
    __syncthreads();
    sc[e] += v;
    __syncthreads();
  }
  int base = sc[e] - total;   // exclusive
  eoff[e] = base;
  if (e == 1023) eoff[1024] = sc[1023];
  for (int b = 0; b < NBLK; b++) ebh[b*N_EDGES + e] += base;
}

// Scan coarse-node histograms -> cbase[197] + per-block bases (in place in nbh)
__global__ __launch_bounds__(256) void nscan_kernel(
    int* __restrict__ nbh, int* __restrict__ cbase)
{
  __shared__ int sc[256];
  int c = threadIdx.x;
  int total = 0;
  if (c < NCB){
    for (int b = 0; b < NBLK; b++){
      int idx = b*NCB + c;
      int t = nbh[idx];
      nbh[idx] = total;
      total += t;
    }
  }
  sc[c] = (c < NCB) ? total : 0; __syncthreads();
  for (int off=1; off<256; off<<=1){
    int v = (c >= off) ? sc[c-off] : 0;
    __syncthreads();
    sc[c] += v;
    __syncthreads();
  }
  int base = sc[c] - ((c < NCB) ? total : 0);
  if (c < NCB) cbase[c] = base;
  if (c == NCB-1) cbase[NCB] = sc[c];
  __syncthreads();
  if (c < NCB)
    for (int b = 0; b < NBLK; b++) nbh[b*NCB + c] += base;
}

// Pass 2: deterministic scatter via LDS cursors (no global atomics)
__global__ __launch_bounds__(256) void scatter_kernel(
    const int* __restrict__ nidx, const int* __restrict__ eidx,
    const int* __restrict__ ebh, const int* __restrict__ nbh,
    int* __restrict__ enodes, uint32_t* __restrict__ pairs)
{
  __shared__ int cure[N_EDGES];
  __shared__ int curn[NCB];
  int tid = threadIdx.x, blk = blockIdx.x;
  for (int l = tid; l < N_EDGES; l += 256) cure[l] = ebh[blk*N_EDGES + l];
  for (int l = tid; l < NCB; l += 256)     curn[l] = nbh[blk*NCB + l];
  __syncthreads();
  int base = blk*CHUNK;
  for (int it = 0; it < ITERS; it++){
    int i = base + it*256 + tid;
    int v = nidx[i], e = eidx[i];
    int pe = atomicAdd(&cure[e], 1);
    enodes[pe] = v;
    int pn = atomicAdd(&curn[v >> 10], 1);
    pairs[pn] = ((uint32_t)v << 10) | (uint32_t)e;
  }
}

// Build node CSR: one block per coarse bucket (1024 nodes, ~8K entries, L2-resident)
__global__ __launch_bounds__(256) void node_build_kernel(
    const uint32_t* __restrict__ pairs, const int* __restrict__ cbase,
    int* __restrict__ noff, int* __restrict__ nedges)
{
  __shared__ int cnt[1024];
  __shared__ int off[1024];
  __shared__ int part[256];
  int tid = threadIdx.x, c = blockIdx.x;
  int n0 = c << 10;
  int nloc = min(1024, N_NODES - n0);
  int s = cbase[c], e = cbase[c+1];
  #pragma unroll
  for (int l = tid; l < 1024; l += 256) cnt[l] = 0;
  __syncthreads();
  for (int i = s + tid; i < e; i += 256)
    atomicAdd(&cnt[(pairs[i] >> 10) & 1023], 1);
  __syncthreads();
  int c0 = cnt[tid*4], c1 = cnt[tid*4+1], c2 = cnt[tid*4+2], c3 = cnt[tid*4+3];
  int sum = c0+c1+c2+c3;
  part[tid] = sum; __syncthreads();
  for (int o=1; o<256; o<<=1){
    int v = (tid >= o) ? part[tid-o] : 0;
    __syncthreads();
    part[tid] += v;
    __syncthreads();
  }
  int pb = part[tid] - sum;   // exclusive over 4-groups
  off[tid*4]   = pb;
  off[tid*4+1] = pb + c0;
  off[tid*4+2] = pb + c0 + c1;
  off[tid*4+3] = pb + c0 + c1 + c2;
  __syncthreads();
  for (int l = tid; l < nloc; l += 256) noff[n0 + l] = s + off[l];
  if (c == 0 && tid == 0) noff[N_NODES] = NNZ_C;
  __syncthreads();
  for (int i = s + tid; i < e; i += 256){
    uint32_t p = pairs[i];
    int local = (p >> 10) & 1023;
    int pos = s + atomicAdd(&off[local], 1);
    nedges[pos] = (int)(p & 1023);
  }
}

// ---------------- GEMM: [N,128] @ [128, CH*128], MFMA 16x16x32 bf16 ----------------
template<bool IN_F32, bool OUT_F32, int CH, bool ACT>
__global__ __launch_bounds__(256, 2) void gemm_kernel(
    const void* __restrict__ in, void* __restrict__ out,
    const short* __restrict__ Wt, const float* __restrict__ bias)
{
  __shared__ short Atile[32][136];
  const int tid  = threadIdx.x;
  const int lane = tid & 63;
  const int w    = tid >> 6;
  const int l15  = lane & 15;
  const int quad = lane >> 4;

  short8 bfrag[CH][2][4];
  #pragma unroll
  for (int j = 0; j < CH; j++)
    #pragma unroll
    for (int nt = 0; nt < 2; nt++){
      const short* bp = Wt + (j*128 + w*32 + nt*16 + l15)*128 + quad*8;
      #pragma unroll
      for (int ks = 0; ks < 4; ks++)
        bfrag[j][nt][ks] = *(const short8*)(bp + ks*32);
    }

  float bv[ACT ? 3 : 1][2];
  if (ACT){
    #pragma unroll
    for (int j = 0; j < 3; j++)
      #pragma unroll
      for (int nt = 0; nt < 2; nt++)
        bv[j][nt] = bias[j*128 + w*32 + nt*16 + l15];
  }

  const int arow = tid >> 3;          // 0..31
  const int aseg = (tid & 7) * 2;     // 32B contiguous / thread

  short8 pre0, pre1;
  auto loadA = [&](int t){
    int off = (t*32 + arow)*128 + aseg*8;
    if (IN_F32){
      const float* f = (const float*)in + off;
      f32x4 q0 = ((const f32x4*)f)[0];
      f32x4 q1 = ((const f32x4*)f)[1];
      f32x4 q2 = ((const f32x4*)f)[2];
      f32x4 q3 = ((const f32x4*)f)[3];
      short8 t0, t1;
      #pragma unroll
      for (int u = 0; u < 4; u++){
        t0[u]   = (short)f2bf(q0[u]);
        t0[u+4] = (short)f2bf(q1[u]);
        t1[u]   = (short)f2bf(q2[u]);
        t1[u+4] = (short)f2bf(q3[u]);
      }
      pre0 = t0; pre1 = t1;
    } else {
      const short* hp = (const short*)in + off;
      pre0 = *(const short8*)hp;
      pre1 = *(const short8*)(hp + 8);
    }
  };

  int t = blockIdx.x;
  loadA(t);
  for (;;){
    __syncthreads();
    *(short8*)&Atile[arow][aseg*8]     = pre0;
    *(short8*)&Atile[arow][aseg*8 + 8] = pre1;
    __syncthreads();
    int tn = t + gridDim.x;
    if (tn < NT_TILES) loadA(tn);

    const int base = t*32;
    #pragma unroll
    for (int rt = 0; rt < 2; rt++){
      short8 af[4];
      #pragma unroll
      for (int ks = 0; ks < 4; ks++)
        af[ks] = *(const short8*)&Atile[rt*16 + l15][ks*32 + quad*8];

      f32x4 acc[CH][2];
      #pragma unroll
      for (int j = 0; j < CH; j++)
        #pragma unroll
        for (int nt = 0; nt < 2; nt++){
          acc[j][nt] = (f32x4){0.f, 0.f, 0.f, 0.f};
          #pragma unroll
          for (int ks = 0; ks < 4; ks++)
            acc[j][nt] = __builtin_amdgcn_mfma_f32_16x16x32_bf16(
                af[ks], bfrag[j][nt][ks], acc[j][nt], 0, 0, 0);
        }

      #pragma unroll
      for (int nt = 0; nt < 2; nt++){
        int col = w*32 + nt*16 + l15;
        #pragma unroll
        for (int r = 0; r < 4; r++){
          int row = base + rt*16 + quad*4 + r;
          float v;
          if (ACT){
            float c2 = acc[1][nt][r] + bv[1][nt];
            float sg = 1.f / (1.f + __expf(-c2));
            v = acc[0][nt][r] + bv[0][nt] + sg + acc[2][nt][r] + bv[2][nt];
            v = fmaxf(v, 0.f);
          } else {
            v = acc[0][nt][r];
          }
          if (OUT_F32) ((float*)out)[row*128 + col] = v;
          else ((unsigned short*)out)[row*128 + col] = f2bf(v);
        }
      }
    }
    if (tn >= NT_TILES) break;
    t = tn;
  }
}

// ---------------- edge aggregation: m[e] = (1/|e|) * sum_{v in e} xp[v] ----------------
__global__ __launch_bounds__(256) void edge_sum_kernel(
    const unsigned short* __restrict__ xp, const int* __restrict__ eoff,
    const int* __restrict__ enodes, float* __restrict__ m)
{
  int e = blockIdx.x;
  int s = eoff[e], tend = eoff[e+1];
  int tid = threadIdx.x;
  int r8 = tid >> 5, ch = tid & 31;
  float a0 = 0.f, a1 = 0.f, a2 = 0.f, a3 = 0.f;
  for (int i = s + r8; i < tend; i += 8){
    int node = enodes[i];
    uint2 raw = *(const uint2*)(xp + node*128 + ch*4);
    a0 += u2f(raw.x << 16);
    a1 += u2f(raw.x & 0xffff0000u);
    a2 += u2f(raw.y << 16);
    a3 += u2f(raw.y & 0xffff0000u);
  }
  __shared__ float red[8][132];
  red[r8][ch*4+0] = a0; red[r8][ch*4+1] = a1;
  red[r8][ch*4+2] = a2; red[r8][ch*4+3] = a3;
  __syncthreads();
  if (tid < 128){
    float sum = 0.f;
    #pragma unroll
    for (int r = 0; r < 8; r++) sum += red[r][tid];
    int cnt = tend - s;
    float be = cnt ? (1.f / (float)cnt) : 0.f;
    m[e*128 + tid] = sum * be;
  }
}

// ---------------- node aggregation: out[v] = (1/deg) * sum_{e ni v} m[e] + b ----------------
__global__ __launch_bounds__(256) void node_out_kernel(
    const float* __restrict__ m, const int* __restrict__ noff,
    const int* __restrict__ nedges, const float* __restrict__ hb,
    unsigned int* __restrict__ outp)
{
  int gw   = (blockIdx.x*256 + threadIdx.x) >> 6;
  int lane = threadIdx.x & 63;
  int nw   = (gridDim.x*256) >> 6;
  float b0 = hb[lane*2], b1 = hb[lane*2+1];
  for (int v = gw; v < N_NODES; v += nw){
    int s = noff[v], e = noff[v+1];
    float a0 = 0.f, a1 = 0.f;
    for (int i = s; i < e; i++){
      int ed = nedges[i];
      float2 mm = *(const float2*)(m + ed*128 + lane*2);
      a0 += mm.x; a1 += mm.y;
    }
    float dn = (e > s) ? 1.f / (float)(e - s) : 0.f;
    a0 = a0*dn + b0;
    a1 = a1*dn + b1;
    outp[v*64 + lane] = ((uint32_t)f2bf(a1) << 16) | (uint32_t)f2bf(a0);
  }
}

// ---------------- host launch ----------------
extern "C" void kernel_launch(void* const* d_in, const int* in_sizes, int n_in,
                              void* d_out, int out_size, void* d_ws, size_t ws_size,
                              hipStream_t stream)
{
  (void)in_sizes; (void)n_in; (void)out_size; (void)ws_size;
  const float* x   = (const float*)d_in[0];
  const float* tbW = (const float*)d_in[1];
  const float* tbb = (const float*)d_in[2];
  const float* hgW = (const float*)d_in[3];
  const float* hgb = (const float*)d_in[4];
  const int* nidx  = (const int*)d_in[6];
  const int* eidx  = (const int*)d_in[7];
  float* out = (float*)d_out;

  char* p = (char*)d_ws;
  auto alloc = [&](size_t sz){ void* r = (void*)p; p += (sz + 255) & ~(size_t)255; return r; };
  unsigned short* hA = (unsigned short*)alloc((size_t)N_NODES*DIM*2);  // 51.2 MB
  unsigned short* hB = (unsigned short*)alloc((size_t)N_NODES*DIM*2);  // 51.2 MB
  float* m    = (float*)alloc((size_t)N_EDGES*DIM*4);                  // 512 KB
  short* WtTb = (short*)alloc((size_t)5*384*128*2);
  short* WtHg = (short*)alloc((size_t)2*128*128*2);
  int* ebh  = (int*)alloc((size_t)NBLK*N_EDGES*4);    // 1.0 MB
  int* nbh  = (int*)alloc((size_t)NBLK*NCB*4);        // 0.2 MB
  int* eoff = (int*)alloc((N_EDGES+1)*4);
  int* cbase= (int*)alloc((NCB+1)*4);
  int* noff = (int*)alloc((size_t)(N_NODES+1)*4);
  int* enodes = (int*)alloc((size_t)NNZ_C*4);
  int* nedges = (int*)alloc((size_t)NNZ_C*4);
  uint32_t* pairs = (uint32_t*)alloc((size_t)NNZ_C*4);

  prep_tb_w<<<960, 256, 0, stream>>>(tbW, WtTb);
  prep_hg_w<<<128, 256, 0, stream>>>(hgW, WtHg);

  // CSR build (deterministic, no global atomics)
  hist_kernel<<<NBLK, 256, 0, stream>>>(nidx, eidx, ebh, nbh);
  escan_kernel<<<1, 1024, 0, stream>>>(ebh, eoff);
  nscan_kernel<<<1, 256, 0, stream>>>(nbh, cbase);
  scatter_kernel<<<NBLK, 256, 0, stream>>>(nidx, eidx, ebh, nbh, enodes, pairs);
  node_build_kernel<<<NCB, 256, 0, stream>>>(pairs, cbase, noff, nedges);

  // TB0: x (fp32) -> hA (bf16)
  gemm_kernel<true,  false, 3, true ><<<1024, 256, 0, stream>>>(x,  hA, WtTb, tbb);
  // conv0
  gemm_kernel<false, false, 1, false><<<1024, 256, 0, stream>>>(hA, hB, WtHg, nullptr);
  edge_sum_kernel<<<N_EDGES, 256, 0, stream>>>(hB, eoff, enodes, m);
  node_out_kernel<<<2048, 256, 0, stream>>>(m, noff, nedges, hgb, (unsigned int*)hA);
  // TB1, TB2
  gemm_kernel<false, false, 3, true ><<<1024, 256, 0, stream>>>(hA, hB, WtTb + 1*49152, tbb + 1*384);
  gemm_kernel<false, false, 3, true ><<<1024, 256, 0, stream>>>(hB, hA, WtTb + 2*49152, tbb + 2*384);
  // conv1
  gemm_kernel<false, false, 1, false><<<1024, 256, 0, stream>>>(hA, hB, WtHg + 16384, nullptr);
  edge_sum_kernel<<<N_EDGES, 256, 0, stream>>>(hB, eoff, enodes, m);
  node_out_kernel<<<2048, 256, 0, stream>>>(m, noff, nedges, hgb + 128, (unsigned int*)hA);
  // TB3, TB4 (final -> fp32 d_out)
  gemm_kernel<false, false, 3, true ><<<1024, 256, 0, stream>>>(hA, hB, WtTb + 3*49152, tbb + 3*384);
  gemm_kernel<false, true,  3, true ><<<1024, 256, 0, stream>>>(hB, out, WtTb + 4*49152, tbb + 4*384);
}

// Round 3
// 859.195 us; speedup vs baseline: 1.8840x; 1.1530x over previous
//
#include <hip/hip_runtime.h>
#include <stdint.h>

// ---------------- constants ----------------
#define N_NODES 200000
#define DIM     128
#define N_EDGES 1024
#define NNZ_C   1600000
#define NT_TILES 6250        // N_NODES / 32 exactly

// CSR-build binning
#define NBLK   250           // histogram/scatter blocks
#define CHUNK  6400          // NNZ / NBLK
#define ITERS  25            // CHUNK / 256
#define NCB    196           // coarse node buckets of 1024 nodes

typedef __attribute__((ext_vector_type(8))) short short8;   // 8 bf16 (4 VGPRs)
typedef __attribute__((ext_vector_type(4))) float f32x4;

__device__ __forceinline__ float u2f(uint32_t u){ union{uint32_t u;float f;} x; x.u=u; return x.f; }
__device__ __forceinline__ uint32_t f2u(float f){ union{uint32_t u;float f;} x; x.f=f; return x.u; }
__device__ __forceinline__ unsigned short f2bf(float f){
  uint32_t u = f2u(f);
  u += 0x7fffu + ((u >> 16) & 1u);      // RNE
  return (unsigned short)(u >> 16);
}

// ---------------- weight prep ----------------
__global__ void prep_tb_w(const float* __restrict__ W, short* __restrict__ Wt){
  int i = blockIdx.x*256 + threadIdx.x;
  if (i >= 5*384*128) return;
  int k   = i & 127;
  int col = (i >> 7) % 384;
  int s   = i / 49152;
  int j = col >> 7, n = col & 127;
  Wt[i] = (short)f2bf(W[((s*3 + j)*128 + k)*128 + n]);
}
// hgW fp32 transposed: Wtf[g][n][k] = W[g][k][n]
__global__ void prep_hg_wf(const float* __restrict__ W, float* __restrict__ Wtf){
  int i = blockIdx.x*256 + threadIdx.x;
  if (i >= 2*128*128) return;
  int k = i & 127;
  int n = (i >> 7) & 127;
  int g = i >> 14;
  Wtf[i] = W[(g*128 + k)*128 + n];
}

// ---------------- CSR build: deterministic binned counting sort ----------------
__global__ __launch_bounds__(256) void hist_kernel(
    const int* __restrict__ nidx, const int* __restrict__ eidx,
    int* __restrict__ ebh, int* __restrict__ nbh)
{
  __shared__ int eh[N_EDGES];
  __shared__ int nh[NCB];
  int tid = threadIdx.x, blk = blockIdx.x;
  #pragma unroll
  for (int l = tid; l < N_EDGES; l += 256) eh[l] = 0;
  for (int l = tid; l < NCB; l += 256) nh[l] = 0;
  __syncthreads();
  int base = blk*CHUNK;
  for (int it = 0; it < ITERS; it++){
    int i = base + it*256 + tid;
    atomicAdd(&eh[eidx[i]], 1);
    atomicAdd(&nh[nidx[i] >> 10], 1);
  }
  __syncthreads();
  for (int l = tid; l < N_EDGES; l += 256) ebh[blk*N_EDGES + l] = eh[l];
  for (int l = tid; l < NCB; l += 256) nbh[blk*NCB + l] = nh[l];
}

__global__ __launch_bounds__(1024) void escan_kernel(
    int* __restrict__ ebh, int* __restrict__ eoff)
{
  __shared__ int sc[1024];
  int e = threadIdx.x;
  int total = 0;
  #pragma unroll 10
  for (int b = 0; b < NBLK; b++){
    int idx = b*N_EDGES + e;
    int t = ebh[idx];
    ebh[idx] = total;
    total += t;
  }
  sc[e] = total; __syncthreads();
  for (int off=1; off<1024; off<<=1){
    int v = (e >= off) ? sc[e-off] : 0;
    __syncthreads();
    sc[e] += v;
    __syncthreads();
  }
  int base = sc[e] - total;   // exclusive
  eoff[e] = base;
  if (e == 1023) eoff[1024] = sc[1023];
  #pragma unroll 10
  for (int b = 0; b < NBLK; b++) ebh[b*N_EDGES + e] += base;
}

__global__ __launch_bounds__(256) void nscan_kernel(
    int* __restrict__ nbh, int* __restrict__ cbase)
{
  __shared__ int sc[256];
  int c = threadIdx.x;
  int total = 0;
  if (c < NCB){
    #pragma unroll 10
    for (int b = 0; b < NBLK; b++){
      int idx = b*NCB + c;
      int t = nbh[idx];
      nbh[idx] = total;
      total += t;
    }
  }
  sc[c] = (c < NCB) ? total : 0; __syncthreads();
  for (int off=1; off<256; off<<=1){
    int v = (c >= off) ? sc[c-off] : 0;
    __syncthreads();
    sc[c] += v;
    __syncthreads();
  }
  int base = sc[c] - ((c < NCB) ? total : 0);
  if (c < NCB) cbase[c] = base;
  if (c == NCB-1) cbase[NCB] = sc[c];
  __syncthreads();
  if (c < NCB){
    #pragma unroll 10
    for (int b = 0; b < NBLK; b++) nbh[b*NCB + c] += base;
  }
}

__global__ __launch_bounds__(256) void scatter_kernel(
    const int* __restrict__ nidx, const int* __restrict__ eidx,
    const int* __restrict__ ebh, const int* __restrict__ nbh,
    int* __restrict__ enodes, uint32_t* __restrict__ pairs)
{
  __shared__ int cure[N_EDGES];
  __shared__ int curn[NCB];
  int tid = threadIdx.x, blk = blockIdx.x;
  for (int l = tid; l < N_EDGES; l += 256) cure[l] = ebh[blk*N_EDGES + l];
  for (int l = tid; l < NCB; l += 256)     curn[l] = nbh[blk*NCB + l];
  __syncthreads();
  int base = blk*CHUNK;
  for (int it = 0; it < ITERS; it++){
    int i = base + it*256 + tid;
    int v = nidx[i], e = eidx[i];
    int pe = atomicAdd(&cure[e], 1);
    enodes[pe] = v;
    int pn = atomicAdd(&curn[v >> 10], 1);
    pairs[pn] = ((uint32_t)v << 10) | (uint32_t)e;
  }
}

__global__ __launch_bounds__(256) void node_build_kernel(
    const uint32_t* __restrict__ pairs, const int* __restrict__ cbase,
    int* __restrict__ noff, int* __restrict__ nedges)
{
  __shared__ int cnt[1024];
  __shared__ int off[1024];
  __shared__ int part[256];
  int tid = threadIdx.x, c = blockIdx.x;
  int n0 = c << 10;
  int nloc = min(1024, N_NODES - n0);
  int s = cbase[c], e = cbase[c+1];
  #pragma unroll
  for (int l = tid; l < 1024; l += 256) cnt[l] = 0;
  __syncthreads();
  for (int i = s + tid; i < e; i += 256)
    atomicAdd(&cnt[(pairs[i] >> 10) & 1023], 1);
  __syncthreads();
  int c0 = cnt[tid*4], c1 = cnt[tid*4+1], c2 = cnt[tid*4+2], c3 = cnt[tid*4+3];
  int sum = c0+c1+c2+c3;
  part[tid] = sum; __syncthreads();
  for (int o=1; o<256; o<<=1){
    int v = (tid >= o) ? part[tid-o] : 0;
    __syncthreads();
    part[tid] += v;
    __syncthreads();
  }
  int pb = part[tid] - sum;
  off[tid*4]   = pb;
  off[tid*4+1] = pb + c0;
  off[tid*4+2] = pb + c0 + c1;
  off[tid*4+3] = pb + c0 + c1 + c2;
  __syncthreads();
  for (int l = tid; l < nloc; l += 256) noff[n0 + l] = s + off[l];
  if (c == 0 && tid == 0) noff[N_NODES] = NNZ_C;
  __syncthreads();
  for (int i = s + tid; i < e; i += 256){
    uint32_t p = pairs[i];
    int local = (p >> 10) & 1023;
    int pos = s + atomicAdd(&off[local], 1);
    nedges[pos] = (int)(p & 1023);
  }
}

// ---------------- GEMM: [N,128] @ [128, 3*128], MFMA 16x16x32 bf16 ----------------
// OUT_MODE: 0 = bf16, 1 = f32, 2 = fp8(e4m3)
template<bool IN_F32, int OUT_MODE>
__global__ __launch_bounds__(256, 2) void gemm_kernel(
    const void* __restrict__ in, void* __restrict__ out,
    const short* __restrict__ Wt, const float* __restrict__ bias)
{
  __shared__ short Atile[32][136];
  const int tid  = threadIdx.x;
  const int lane = tid & 63;
  const int w    = tid >> 6;
  const int l15  = lane & 15;
  const int quad = lane >> 4;

  short8 bfrag[3][2][4];
  #pragma unroll
  for (int j = 0; j < 3; j++)
    #pragma unroll
    for (int nt = 0; nt < 2; nt++){
      const short* bp = Wt + (j*128 + w*32 + nt*16 + l15)*128 + quad*8;
      #pragma unroll
      for (int ks = 0; ks < 4; ks++)
        bfrag[j][nt][ks] = *(const short8*)(bp + ks*32);
    }

  float bv[3][2];
  #pragma unroll
  for (int j = 0; j < 3; j++)
    #pragma unroll
    for (int nt = 0; nt < 2; nt++)
      bv[j][nt] = bias[j*128 + w*32 + nt*16 + l15];

  const int arow = tid >> 3;
  const int aseg = (tid & 7) * 2;

  short8 pre0, pre1;
  auto loadA = [&](int t){
    int off = (t*32 + arow)*128 + aseg*8;
    if (IN_F32){
      const float* f = (const float*)in + off;
      f32x4 q0 = ((const f32x4*)f)[0];
      f32x4 q1 = ((const f32x4*)f)[1];
      f32x4 q2 = ((const f32x4*)f)[2];
      f32x4 q3 = ((const f32x4*)f)[3];
      short8 t0, t1;
      #pragma unroll
      for (int u = 0; u < 4; u++){
        t0[u]   = (short)f2bf(q0[u]);
        t0[u+4] = (short)f2bf(q1[u]);
        t1[u]   = (short)f2bf(q2[u]);
        t1[u+4] = (short)f2bf(q3[u]);
      }
      pre0 = t0; pre1 = t1;
    } else {
      const short* hp = (const short*)in + off;
      pre0 = *(const short8*)hp;
      pre1 = *(const short8*)(hp + 8);
    }
  };

  int t = blockIdx.x;
  loadA(t);
  for (;;){
    __syncthreads();
    *(short8*)&Atile[arow][aseg*8]     = pre0;
    *(short8*)&Atile[arow][aseg*8 + 8] = pre1;
    __syncthreads();
    int tn = t + gridDim.x;
    if (tn < NT_TILES) loadA(tn);

    const int base = t*32;
    #pragma unroll
    for (int rt = 0; rt < 2; rt++){
      short8 af[4];
      #pragma unroll
      for (int ks = 0; ks < 4; ks++)
        af[ks] = *(const short8*)&Atile[rt*16 + l15][ks*32 + quad*8];

      f32x4 acc[3][2];
      #pragma unroll
      for (int j = 0; j < 3; j++)
        #pragma unroll
        for (int nt = 0; nt < 2; nt++){
          acc[j][nt] = (f32x4){0.f, 0.f, 0.f, 0.f};
          #pragma unroll
          for (int ks = 0; ks < 4; ks++)
            acc[j][nt] = __builtin_amdgcn_mfma_f32_16x16x32_bf16(
                af[ks], bfrag[j][nt][ks], acc[j][nt], 0, 0, 0);
        }

      #pragma unroll
      for (int nt = 0; nt < 2; nt++){
        int col = w*32 + nt*16 + l15;
        #pragma unroll
        for (int r = 0; r < 4; r++){
          int row = base + rt*16 + quad*4 + r;
          float c2 = acc[1][nt][r] + bv[1][nt];
          float sg = 1.f / (1.f + __expf(-c2));
          float v = acc[0][nt][r] + bv[0][nt] + sg + acc[2][nt][r] + bv[2][nt];
          v = fmaxf(v, 0.f);
          if (OUT_MODE == 1) ((float*)out)[row*128 + col] = v;
          else if (OUT_MODE == 0) ((unsigned short*)out)[row*128 + col] = f2bf(v);
          else {
            int pk = __builtin_amdgcn_cvt_pk_fp8_f32(v, v, 0, false);
            ((unsigned char*)out)[row*128 + col] = (unsigned char)(pk & 0xff);
          }
        }
      }
    }
    if (tn >= NT_TILES) break;
    t = tn;
  }
}

// ---------------- edge gather-sum of fp8 h: s_e[e] += sum_{v in e} h8[v] ----------------
// 4 blocks per edge; LDS partial reduce; fp32 atomicAdd into L2-resident s_e.
__global__ __launch_bounds__(256) void edge_gather_kernel(
    const unsigned char* __restrict__ h8, const int* __restrict__ eoff,
    const int* __restrict__ enodes, float* __restrict__ s_e)
{
  int bid = blockIdx.x;
  int e = bid >> 2, q = bid & 3;
  int s = eoff[e], en = eoff[e+1];
  int tid = threadIdx.x;
  int rr   = tid >> 5;              // 8 row slots per block
  int slot = q*8 + rr;              // 0..31 across the 4 blocks
  int ch   = tid & 31;              // 4 channels each
  float a0=0.f, a1=0.f, a2=0.f, a3=0.f;
  int i = s + slot;
  int nd = (i < en) ? enodes[i] : 0;
  while (i < en){
    int inx = i + 32;
    int ndn = (inx < en) ? enodes[inx] : 0;   // prefetch next index
    uint32_t raw = *(const uint32_t*)(h8 + (size_t)nd*128 + ch*4);
    auto lo = __builtin_amdgcn_cvt_pk_f32_fp8(raw, false);
    auto hi = __builtin_amdgcn_cvt_pk_f32_fp8(raw, true);
    a0 += lo[0]; a1 += lo[1]; a2 += hi[0]; a3 += hi[1];
    i = inx; nd = ndn;
  }
  __shared__ float red[8][132];
  red[rr][ch*4+0]=a0; red[rr][ch*4+1]=a1; red[rr][ch*4+2]=a2; red[rr][ch*4+3]=a3;
  __syncthreads();
  if (tid < 128){
    float sum = 0.f;
    #pragma unroll
    for (int r = 0; r < 8; r++) sum += red[r][tid];
    atomicAdd(&s_e[e*128 + tid], sum);
  }
}

// ---------------- tiny GEMM: m[e] = (s_e[e] * Be) @ W  (fp32) ----------------
__global__ __launch_bounds__(128) void egemm_kernel(
    const float* __restrict__ s_e, const int* __restrict__ eoff,
    const float* __restrict__ Wtf, float* __restrict__ m)
{
  __shared__ float srow[128];
  int e = blockIdx.x, n = threadIdx.x;
  srow[n] = s_e[e*128 + n];
  __syncthreads();
  int deg = eoff[e+1] - eoff[e];
  float be = deg > 0 ? 1.f/(float)deg : 0.f;
  const f32x4* w4 = (const f32x4*)(Wtf + n*128);
  float acc = 0.f;
  #pragma unroll
  for (int k = 0; k < 32; k++){
    f32x4 qv = w4[k];
    acc += qv[0]*srow[k*4] + qv[1]*srow[k*4+1] + qv[2]*srow[k*4+2] + qv[3]*srow[k*4+3];
  }
  m[e*128 + n] = acc * be;
}

// ---------------- node aggregation: out[v] = (1/deg) * sum_{e ni v} m[e] + b ----------------
__global__ __launch_bounds__(256) void node_out_kernel(
    const float* __restrict__ m, const int* __restrict__ noff,
    const int* __restrict__ nedges, const float* __restrict__ hb,
    unsigned int* __restrict__ outp)
{
  int gw   = (blockIdx.x*256 + threadIdx.x) >> 6;
  int lane = threadIdx.x & 63;
  int nw   = (gridDim.x*256) >> 6;
  float b0 = hb[lane*2], b1 = hb[lane*2+1];
  for (int v = gw; v < N_NODES; v += nw){
    int s = noff[v], e = noff[v+1];
    float a0 = 0.f, a1 = 0.f;
    for (int i = s; i < e; i++){
      int ed = nedges[i];
      float2 mm = *(const float2*)(m + ed*128 + lane*2);
      a0 += mm.x; a1 += mm.y;
    }
    float dn = (e > s) ? 1.f / (float)(e - s) : 0.f;
    a0 = a0*dn + b0;
    a1 = a1*dn + b1;
    outp[v*64 + lane] = ((uint32_t)f2bf(a1) << 16) | (uint32_t)f2bf(a0);
  }
}

// ---------------- host launch ----------------
extern "C" void kernel_launch(void* const* d_in, const int* in_sizes, int n_in,
                              void* d_out, int out_size, void* d_ws, size_t ws_size,
                              hipStream_t stream)
{
  (void)in_sizes; (void)n_in; (void)out_size; (void)ws_size;
  const float* x   = (const float*)d_in[0];
  const float* tbW = (const float*)d_in[1];
  const float* tbb = (const float*)d_in[2];
  const float* hgW = (const float*)d_in[3];
  const float* hgb = (const float*)d_in[4];
  const int* nidx  = (const int*)d_in[6];
  const int* eidx  = (const int*)d_in[7];
  float* out = (float*)d_out;

  char* p = (char*)d_ws;
  auto alloc = [&](size_t sz){ void* r = (void*)p; p += (sz + 255) & ~(size_t)255; return r; };
  unsigned short* hA = (unsigned short*)alloc((size_t)N_NODES*DIM*2);  // 51.2 MB
  unsigned short* hB = (unsigned short*)alloc((size_t)N_NODES*DIM*2);  // 51.2 MB
  unsigned char*  h8 = (unsigned char*)alloc((size_t)N_NODES*DIM);     // 25.6 MB
  float* s_e  = (float*)alloc((size_t)N_EDGES*DIM*4);                  // 512 KB
  float* m    = (float*)alloc((size_t)N_EDGES*DIM*4);                  // 512 KB
  short* WtTb = (short*)alloc((size_t)5*384*128*2);
  float* Wtf  = (float*)alloc((size_t)2*128*128*4);
  int* ebh  = (int*)alloc((size_t)NBLK*N_EDGES*4);
  int* nbh  = (int*)alloc((size_t)NBLK*NCB*4);
  int* eoff = (int*)alloc((N_EDGES+1)*4);
  int* cbase= (int*)alloc((NCB+1)*4);
  int* noff = (int*)alloc((size_t)(N_NODES+1)*4);
  int* enodes = (int*)alloc((size_t)NNZ_C*4);
  int* nedges = (int*)alloc((size_t)NNZ_C*4);
  uint32_t* pairs = (uint32_t*)h8;   // transient: consumed by node_build before h8 is written

  prep_tb_w<<<960, 256, 0, stream>>>(tbW, WtTb);
  prep_hg_wf<<<128, 256, 0, stream>>>(hgW, Wtf);

  // CSR build (deterministic, no global atomics)
  hist_kernel<<<NBLK, 256, 0, stream>>>(nidx, eidx, ebh, nbh);
  escan_kernel<<<1, 1024, 0, stream>>>(ebh, eoff);
  nscan_kernel<<<1, 256, 0, stream>>>(nbh, cbase);
  scatter_kernel<<<NBLK, 256, 0, stream>>>(nidx, eidx, ebh, nbh, enodes, pairs);
  node_build_kernel<<<NCB, 256, 0, stream>>>(pairs, cbase, noff, nedges);

  // TB0: x (fp32) -> h8 (fp8)
  gemm_kernel<true, 2><<<1024, 256, 0, stream>>>(x, h8, WtTb, tbb);
  // conv0: gather-sum h8 over edges -> s_e; m = (s_e*Be)@W0; node agg -> hA (bf16)
  hipMemsetAsync(s_e, 0, (size_t)N_EDGES*DIM*4, stream);
  edge_gather_kernel<<<4*N_EDGES, 256, 0, stream>>>(h8, eoff, enodes, s_e);
  egemm_kernel<<<N_EDGES, 128, 0, stream>>>(s_e, eoff, Wtf, m);
  node_out_kernel<<<2048, 256, 0, stream>>>(m, noff, nedges, hgb, (unsigned int*)hA);
  // TB1: hA -> hB (bf16), TB2: hB -> h8 (fp8)
  gemm_kernel<false, 0><<<1024, 256, 0, stream>>>(hA, hB, WtTb + 1*49152, tbb + 1*384);
  gemm_kernel<false, 2><<<1024, 256, 0, stream>>>(hB, h8, WtTb + 2*49152, tbb + 2*384);
  // conv1
  hipMemsetAsync(s_e, 0, (size_t)N_EDGES*DIM*4, stream);
  edge_gather_kernel<<<4*N_EDGES, 256, 0, stream>>>(h8, eoff, enodes, s_e);
  egemm_kernel<<<N_EDGES, 128, 0, stream>>>(s_e, eoff, Wtf + 16384, m);
  node_out_kernel<<<2048, 256, 0, stream>>>(m, noff, nedges, hgb + 128, (unsigned int*)hA);
  // TB3: hA -> hB, TB4: hB -> out (fp32)
  gemm_kernel<false, 0><<<1024, 256, 0, stream>>>(hA, hB, WtTb + 3*49152, tbb + 3*384);
  gemm_kernel<false, 1><<<1024, 256, 0, stream>>>(hB, out, WtTb + 4*49152, tbb + 4*384);
}

// Round 4
// 805.152 us; speedup vs baseline: 2.0104x; 1.0671x over previous
//
#include <hip/hip_runtime.h>
#include <stdint.h>

// ---------------- constants ----------------
#define N_NODES 200000
#define DIM     128
#define N_EDGES 1024
#define NNZ_C   1600000
#define NT_TILES 6250        // N_NODES / 32 exactly

// CSR-build binning
#define NBLK   250           // histogram/scatter blocks
#define CHUNK  6400          // NNZ / NBLK
#define ITERS  25            // CHUNK / 256
#define NCB    196           // coarse node buckets of 1024 nodes

typedef __attribute__((ext_vector_type(8))) short short8;   // 8 bf16 (4 VGPRs)
typedef __attribute__((ext_vector_type(4))) float f32x4;

__device__ __forceinline__ float u2f(uint32_t u){ union{uint32_t u;float f;} x; x.u=u; return x.f; }
__device__ __forceinline__ uint32_t f2u(float f){ union{uint32_t u;float f;} x; x.f=f; return x.u; }
__device__ __forceinline__ unsigned short f2bf(float f){
  uint32_t u = f2u(f);
  u += 0x7fffu + ((u >> 16) & 1u);      // RNE
  return (unsigned short)(u >> 16);
}

// ---------------- weight prep ----------------
__global__ void prep_tb_w(const float* __restrict__ W, short* __restrict__ Wt){
  int i = blockIdx.x*256 + threadIdx.x;
  if (i >= 5*384*128) return;
  int k   = i & 127;
  int col = (i >> 7) % 384;
  int s   = i / 49152;
  int j = col >> 7, n = col & 127;
  Wt[i] = (short)f2bf(W[((s*3 + j)*128 + k)*128 + n]);
}
// hgW fp32 transposed: Wtf[g][n][k] = W[g][k][n]
__global__ void prep_hg_wf(const float* __restrict__ W, float* __restrict__ Wtf){
  int i = blockIdx.x*256 + threadIdx.x;
  if (i >= 2*128*128) return;
  int k = i & 127;
  int n = (i >> 7) & 127;
  int g = i >> 14;
  Wtf[i] = W[(g*128 + k)*128 + n];
}

// ---------------- CSR build: deterministic binned counting sort ----------------
__global__ __launch_bounds__(256) void hist_kernel(
    const int* __restrict__ nidx, const int* __restrict__ eidx,
    int* __restrict__ ebh, int* __restrict__ nbh)
{
  __shared__ int eh[N_EDGES];
  __shared__ int nh[NCB];
  int tid = threadIdx.x, blk = blockIdx.x;
  #pragma unroll
  for (int l = tid; l < N_EDGES; l += 256) eh[l] = 0;
  for (int l = tid; l < NCB; l += 256) nh[l] = 0;
  __syncthreads();
  int base = blk*CHUNK;
  for (int it = 0; it < ITERS; it++){
    int i = base + it*256 + tid;
    atomicAdd(&eh[eidx[i]], 1);
    atomicAdd(&nh[nidx[i] >> 10], 1);
  }
  __syncthreads();
  for (int l = tid; l < N_EDGES; l += 256) ebh[blk*N_EDGES + l] = eh[l];
  for (int l = tid; l < NCB; l += 256) nbh[blk*NCB + l] = nh[l];
}

__global__ __launch_bounds__(1024) void escan_kernel(
    int* __restrict__ ebh, int* __restrict__ eoff)
{
  __shared__ int sc[1024];
  int e = threadIdx.x;
  int total = 0;
  #pragma unroll 10
  for (int b = 0; b < NBLK; b++){
    int idx = b*N_EDGES + e;
    int t = ebh[idx];
    ebh[idx] = total;
    total += t;
  }
  sc[e] = total; __syncthreads();
  for (int off=1; off<1024; off<<=1){
    int v = (e >= off) ? sc[e-off] : 0;
    __syncthreads();
    sc[e] += v;
    __syncthreads();
  }
  int base = sc[e] - total;   // exclusive
  eoff[e] = base;
  if (e == 1023) eoff[1024] = sc[1023];
  #pragma unroll 10
  for (int b = 0; b < NBLK; b++) ebh[b*N_EDGES + e] += base;
}

__global__ __launch_bounds__(256) void nscan_kernel(
    int* __restrict__ nbh, int* __restrict__ cbase)
{
  __shared__ int sc[256];
  int c = threadIdx.x;
  int total = 0;
  if (c < NCB){
    #pragma unroll 10
    for (int b = 0; b < NBLK; b++){
      int idx = b*NCB + c;
      int t = nbh[idx];
      nbh[idx] = total;
      total += t;
    }
  }
  sc[c] = (c < NCB) ? total : 0; __syncthreads();
  for (int off=1; off<256; off<<=1){
    int v = (c >= off) ? sc[c-off] : 0;
    __syncthreads();
    sc[c] += v;
    __syncthreads();
  }
  int base = sc[c] - ((c < NCB) ? total : 0);
  if (c < NCB) cbase[c] = base;
  if (c == NCB-1) cbase[NCB] = sc[c];
  __syncthreads();
  if (c < NCB){
    #pragma unroll 10
    for (int b = 0; b < NBLK; b++) nbh[b*NCB + c] += base;
  }
}

__global__ __launch_bounds__(256) void scatter_kernel(
    const int* __restrict__ nidx, const int* __restrict__ eidx,
    const int* __restrict__ ebh, const int* __restrict__ nbh,
    int* __restrict__ enodes, uint32_t* __restrict__ pairs)
{
  __shared__ int cure[N_EDGES];
  __shared__ int curn[NCB];
  int tid = threadIdx.x, blk = blockIdx.x;
  for (int l = tid; l < N_EDGES; l += 256) cure[l] = ebh[blk*N_EDGES + l];
  for (int l = tid; l < NCB; l += 256)     curn[l] = nbh[blk*NCB + l];
  __syncthreads();
  int base = blk*CHUNK;
  for (int it = 0; it < ITERS; it++){
    int i = base + it*256 + tid;
    int v = nidx[i], e = eidx[i];
    int pe = atomicAdd(&cure[e], 1);
    enodes[pe] = v;
    int pn = atomicAdd(&curn[v >> 10], 1);
    pairs[pn] = ((uint32_t)v << 10) | (uint32_t)e;
  }
}

__global__ __launch_bounds__(256) void node_build_kernel(
    const uint32_t* __restrict__ pairs, const int* __restrict__ cbase,
    int* __restrict__ noff, int* __restrict__ nedges)
{
  __shared__ int cnt[1024];
  __shared__ int off[1024];
  __shared__ int part[256];
  int tid = threadIdx.x, c = blockIdx.x;
  int n0 = c << 10;
  int nloc = min(1024, N_NODES - n0);
  int s = cbase[c], e = cbase[c+1];
  #pragma unroll
  for (int l = tid; l < 1024; l += 256) cnt[l] = 0;
  __syncthreads();
  for (int i = s + tid; i < e; i += 256)
    atomicAdd(&cnt[(pairs[i] >> 10) & 1023], 1);
  __syncthreads();
  int c0 = cnt[tid*4], c1 = cnt[tid*4+1], c2 = cnt[tid*4+2], c3 = cnt[tid*4+3];
  int sum = c0+c1+c2+c3;
  part[tid] = sum; __syncthreads();
  for (int o=1; o<256; o<<=1){
    int v = (tid >= o) ? part[tid-o] : 0;
    __syncthreads();
    part[tid] += v;
    __syncthreads();
  }
  int pb = part[tid] - sum;
  off[tid*4]   = pb;
  off[tid*4+1] = pb + c0;
  off[tid*4+2] = pb + c0 + c1;
  off[tid*4+3] = pb + c0 + c1 + c2;
  __syncthreads();
  for (int l = tid; l < nloc; l += 256) noff[n0 + l] = s + off[l];
  if (c == 0 && tid == 0) noff[N_NODES] = NNZ_C;
  __syncthreads();
  for (int i = s + tid; i < e; i += 256){
    uint32_t p = pairs[i];
    int local = (p >> 10) & 1023;
    int pos = s + atomicAdd(&off[local], 1);
    nedges[pos] = (int)(p & 1023);
  }
}

// ---------------- GEMM: [N,128] @ [128, 3*128], MFMA 16x16x32 bf16 ----------------
// OUT_MODE: 0 = bf16, 1 = f32, 2 = fp8(e4m3)
template<bool IN_F32, int OUT_MODE>
__global__ __launch_bounds__(256, 2) void gemm_kernel(
    const void* __restrict__ in, void* __restrict__ out,
    const short* __restrict__ Wt, const float* __restrict__ bias)
{
  __shared__ short Atile[32][136];
  const int tid  = threadIdx.x;
  const int lane = tid & 63;
  const int w    = tid >> 6;
  const int l15  = lane & 15;
  const int quad = lane >> 4;

  short8 bfrag[3][2][4];
  #pragma unroll
  for (int j = 0; j < 3; j++)
    #pragma unroll
    for (int nt = 0; nt < 2; nt++){
      const short* bp = Wt + (j*128 + w*32 + nt*16 + l15)*128 + quad*8;
      #pragma unroll
      for (int ks = 0; ks < 4; ks++)
        bfrag[j][nt][ks] = *(const short8*)(bp + ks*32);
    }

  float bv[3][2];
  #pragma unroll
  for (int j = 0; j < 3; j++)
    #pragma unroll
    for (int nt = 0; nt < 2; nt++)
      bv[j][nt] = bias[j*128 + w*32 + nt*16 + l15];

  const int arow = tid >> 3;
  const int aseg = (tid & 7) * 2;

  short8 pre0, pre1;
  auto loadA = [&](int t){
    int off = (t*32 + arow)*128 + aseg*8;
    if (IN_F32){
      const float* f = (const float*)in + off;
      f32x4 q0 = ((const f32x4*)f)[0];
      f32x4 q1 = ((const f32x4*)f)[1];
      f32x4 q2 = ((const f32x4*)f)[2];
      f32x4 q3 = ((const f32x4*)f)[3];
      short8 t0, t1;
      #pragma unroll
      for (int u = 0; u < 4; u++){
        t0[u]   = (short)f2bf(q0[u]);
        t0[u+4] = (short)f2bf(q1[u]);
        t1[u]   = (short)f2bf(q2[u]);
        t1[u+4] = (short)f2bf(q3[u]);
      }
      pre0 = t0; pre1 = t1;
    } else {
      const short* hp = (const short*)in + off;
      pre0 = *(const short8*)hp;
      pre1 = *(const short8*)(hp + 8);
    }
  };

  int t = blockIdx.x;
  loadA(t);
  for (;;){
    __syncthreads();
    *(short8*)&Atile[arow][aseg*8]     = pre0;
    *(short8*)&Atile[arow][aseg*8 + 8] = pre1;
    __syncthreads();
    int tn = t + gridDim.x;
    if (tn < NT_TILES) loadA(tn);

    const int base = t*32;
    #pragma unroll
    for (int rt = 0; rt < 2; rt++){
      short8 af[4];
      #pragma unroll
      for (int ks = 0; ks < 4; ks++)
        af[ks] = *(const short8*)&Atile[rt*16 + l15][ks*32 + quad*8];

      f32x4 acc[3][2];
      #pragma unroll
      for (int j = 0; j < 3; j++)
        #pragma unroll
        for (int nt = 0; nt < 2; nt++){
          acc[j][nt] = (f32x4){0.f, 0.f, 0.f, 0.f};
          #pragma unroll
          for (int ks = 0; ks < 4; ks++)
            acc[j][nt] = __builtin_amdgcn_mfma_f32_16x16x32_bf16(
                af[ks], bfrag[j][nt][ks], acc[j][nt], 0, 0, 0);
        }

      #pragma unroll
      for (int nt = 0; nt < 2; nt++){
        int col = w*32 + nt*16 + l15;
        #pragma unroll
        for (int r = 0; r < 4; r++){
          int row = base + rt*16 + quad*4 + r;
          float c2 = acc[1][nt][r] + bv[1][nt];
          float sg = 1.f / (1.f + __expf(-c2));
          float v = acc[0][nt][r] + bv[0][nt] + sg + acc[2][nt][r] + bv[2][nt];
          v = fmaxf(v, 0.f);
          if (OUT_MODE == 1) ((float*)out)[row*128 + col] = v;
          else if (OUT_MODE == 0) ((unsigned short*)out)[row*128 + col] = f2bf(v);
          else {
            int pk = __builtin_amdgcn_cvt_pk_fp8_f32(v, v, 0, false);
            ((unsigned char*)out)[row*128 + col] = (unsigned char)(pk & 0xff);
          }
        }
      }
    }
    if (tn >= NT_TILES) break;
    t = tn;
  }
}

// ---------------- edge gather-sum of fp8 h: s_e[e] += sum_{v in e} h8[v] ----------------
__global__ __launch_bounds__(256) void edge_gather_kernel(
    const unsigned char* __restrict__ h8, const int* __restrict__ eoff,
    const int* __restrict__ enodes, float* __restrict__ s_e)
{
  int bid = blockIdx.x;
  int e = bid >> 2, q = bid & 3;
  int s = eoff[e], en = eoff[e+1];
  int tid = threadIdx.x;
  int rr   = tid >> 5;
  int slot = q*8 + rr;
  int ch   = tid & 31;
  float a0=0.f, a1=0.f, a2=0.f, a3=0.f;
  int i = s + slot;
  int nd = (i < en) ? enodes[i] : 0;
  while (i < en){
    int inx = i + 32;
    int ndn = (inx < en) ? enodes[inx] : 0;   // prefetch next index
    uint32_t raw = *(const uint32_t*)(h8 + (size_t)nd*128 + ch*4);
    auto lo = __builtin_amdgcn_cvt_pk_f32_fp8(raw, false);
    auto hi = __builtin_amdgcn_cvt_pk_f32_fp8(raw, true);
    a0 += lo[0]; a1 += lo[1]; a2 += hi[0]; a3 += hi[1];
    i = inx; nd = ndn;
  }
  __shared__ float red[8][132];
  red[rr][ch*4+0]=a0; red[rr][ch*4+1]=a1; red[rr][ch*4+2]=a2; red[rr][ch*4+3]=a3;
  __syncthreads();
  if (tid < 128){
    float sum = 0.f;
    #pragma unroll
    for (int r = 0; r < 8; r++) sum += red[r][tid];
    atomicAdd(&s_e[e*128 + tid], sum);
  }
}

// ---------------- tiny GEMM: m[e] = (s_e[e] * Be) @ W, packed bf16 out ----------------
__global__ __launch_bounds__(128) void egemm_kernel(
    const float* __restrict__ s_e, const int* __restrict__ eoff,
    const float* __restrict__ Wtf, uint32_t* __restrict__ mbf)
{
  __shared__ float srow[128];
  __shared__ float sacc[128];
  int e = blockIdx.x, n = threadIdx.x;
  srow[n] = s_e[e*128 + n];
  __syncthreads();
  int deg = eoff[e+1] - eoff[e];
  float be = deg > 0 ? 1.f/(float)deg : 0.f;
  const f32x4* w4 = (const f32x4*)(Wtf + n*128);
  float acc = 0.f;
  #pragma unroll
  for (int k = 0; k < 32; k++){
    f32x4 qv = w4[k];
    acc += qv[0]*srow[k*4] + qv[1]*srow[k*4+1] + qv[2]*srow[k*4+2] + qv[3]*srow[k*4+3];
  }
  sacc[n] = acc * be;
  __syncthreads();
  if (n < 64){
    uint32_t lo = f2bf(sacc[2*n]);
    uint32_t hi = f2bf(sacc[2*n+1]);
    mbf[e*64 + n] = (hi << 16) | lo;
  }
}

// ---------------- node gather: out[v] = (1/deg)*sum m[e] + b, LDS-staged m ----------------
// grid = NCB buckets x 4 channel-quarters; m quarter (1024x16 uint32 = 64 KB) in LDS,
// XOR-swizzled so random-row gathers spread over all 32 banks.
__global__ __launch_bounds__(256, 2) void node_gather_kernel(
    const uint32_t* __restrict__ mbf, const int* __restrict__ noff,
    const int* __restrict__ nedges, const float* __restrict__ hb,
    uint32_t* __restrict__ outp)
{
  __shared__ uint32_t ml[1024*16];   // 64 KB
  int bid = blockIdx.x;
  int c = bid >> 2, q = bid & 3;
  int tid = threadIdx.x;
  for (int idx = tid; idx < 16384; idx += 256){
    int row = idx >> 4, cc = idx & 15;
    ml[(row << 4) | (cc ^ (row & 15))] = mbf[row*64 + q*16 + cc];
  }
  float bch[32];
  #pragma unroll
  for (int j = 0; j < 32; j++) bch[j] = hb[q*32 + j];
  __syncthreads();

  int n0 = c << 10;
  int nloc = min(1024, N_NODES - n0);
  for (int base = 0; base < nloc; base += 256){
    int li = base + tid;
    bool active = li < nloc;
    int v = n0 + li;
    int s = active ? noff[v] : 0;
    int e = active ? noff[v+1] : 0;
    float acc[32];
    #pragma unroll
    for (int j = 0; j < 32; j++) acc[j] = 0.f;
    for (int i = s; i < e; i++){
      int ed = nedges[i];
      int rb = ed << 4, rx = ed & 15;
      #pragma unroll
      for (int cc = 0; cc < 16; cc++){
        uint32_t r = ml[rb | (cc ^ rx)];
        acc[2*cc]   += u2f(r << 16);
        acc[2*cc+1] += u2f(r & 0xffff0000u);
      }
    }
    if (active){
      float dn = (e > s) ? 1.f/(float)(e - s) : 0.f;
      #pragma unroll
      for (int cc = 0; cc < 16; cc++){
        uint32_t lo = f2bf(acc[2*cc]  *dn + bch[2*cc]);
        uint32_t hi = f2bf(acc[2*cc+1]*dn + bch[2*cc+1]);
        outp[(size_t)v*64 + q*16 + cc] = (hi << 16) | lo;
      }
    }
  }
}

// ---------------- host launch ----------------
extern "C" void kernel_launch(void* const* d_in, const int* in_sizes, int n_in,
                              void* d_out, int out_size, void* d_ws, size_t ws_size,
                              hipStream_t stream)
{
  (void)in_sizes; (void)n_in; (void)out_size; (void)ws_size;
  const float* x   = (const float*)d_in[0];
  const float* tbW = (const float*)d_in[1];
  const float* tbb = (const float*)d_in[2];
  const float* hgW = (const float*)d_in[3];
  const float* hgb = (const float*)d_in[4];
  const int* nidx  = (const int*)d_in[6];
  const int* eidx  = (const int*)d_in[7];
  float* out = (float*)d_out;

  char* p = (char*)d_ws;
  auto alloc = [&](size_t sz){ void* r = (void*)p; p += (sz + 255) & ~(size_t)255; return r; };
  unsigned short* hA = (unsigned short*)alloc((size_t)N_NODES*DIM*2);  // 51.2 MB
  unsigned short* hB = (unsigned short*)alloc((size_t)N_NODES*DIM*2);  // 51.2 MB
  unsigned char*  h8 = (unsigned char*)alloc((size_t)N_NODES*DIM);     // 25.6 MB
  float* s_e  = (float*)alloc((size_t)N_EDGES*DIM*4);                  // 512 KB
  uint32_t* mbf = (uint32_t*)alloc((size_t)N_EDGES*64*4);              // 256 KB
  short* WtTb = (short*)alloc((size_t)5*384*128*2);
  float* Wtf  = (float*)alloc((size_t)2*128*128*4);
  int* ebh  = (int*)alloc((size_t)NBLK*N_EDGES*4);
  int* nbh  = (int*)alloc((size_t)NBLK*NCB*4);
  int* eoff = (int*)alloc((N_EDGES+1)*4);
  int* cbase= (int*)alloc((NCB+1)*4);
  int* noff = (int*)alloc((size_t)(N_NODES+1)*4);
  int* enodes = (int*)alloc((size_t)NNZ_C*4);
  int* nedges = (int*)alloc((size_t)NNZ_C*4);
  uint32_t* pairs = (uint32_t*)h8;   // transient: consumed by node_build before h8 is written

  prep_tb_w<<<960, 256, 0, stream>>>(tbW, WtTb);
  prep_hg_wf<<<128, 256, 0, stream>>>(hgW, Wtf);

  // CSR build (deterministic, no global atomics)
  hist_kernel<<<NBLK, 256, 0, stream>>>(nidx, eidx, ebh, nbh);
  escan_kernel<<<1, 1024, 0, stream>>>(ebh, eoff);
  nscan_kernel<<<1, 256, 0, stream>>>(nbh, cbase);
  scatter_kernel<<<NBLK, 256, 0, stream>>>(nidx, eidx, ebh, nbh, enodes, pairs);
  node_build_kernel<<<NCB, 256, 0, stream>>>(pairs, cbase, noff, nedges);

  // TB0: x (fp32) -> h8 (fp8)
  gemm_kernel<true, 2><<<1024, 256, 0, stream>>>(x, h8, WtTb, tbb);
  // conv0: gather-sum h8 -> s_e; m = (s_e*Be)@W0 (bf16-packed); node gather -> hA (bf16)
  hipMemsetAsync(s_e, 0, (size_t)N_EDGES*DIM*4, stream);
  edge_gather_kernel<<<4*N_EDGES, 256, 0, stream>>>(h8, eoff, enodes, s_e);
  egemm_kernel<<<N_EDGES, 128, 0, stream>>>(s_e, eoff, Wtf, mbf);
  node_gather_kernel<<<4*NCB, 256, 0, stream>>>(mbf, noff, nedges, hgb, (uint32_t*)hA);
  // TB1: hA -> hB (bf16), TB2: hB -> h8 (fp8)
  gemm_kernel<false, 0><<<1024, 256, 0, stream>>>(hA, hB, WtTb + 1*49152, tbb + 1*384);
  gemm_kernel<false, 2><<<1024, 256, 0, stream>>>(hB, h8, WtTb + 2*49152, tbb + 2*384);
  // conv1
  hipMemsetAsync(s_e, 0, (size_t)N_EDGES*DIM*4, stream);
  edge_gather_kernel<<<4*N_EDGES, 256, 0, stream>>>(h8, eoff, enodes, s_e);
  egemm_kernel<<<N_EDGES, 128, 0, stream>>>(s_e, eoff, Wtf + 16384, mbf);
  node_gather_kernel<<<4*NCB, 256, 0, stream>>>(mbf, noff, nedges, hgb + 128, (uint32_t*)hA);
  // TB3: hA -> hB, TB4: hB -> out (fp32)
  gemm_kernel<false, 0><<<1024, 256, 0, stream>>>(hA, hB, WtTb + 3*49152, tbb + 3*384);
  gemm_kernel<false, 1><<<1024, 256, 0, stream>>>(hB, out, WtTb + 4*49152, tbb + 4*384);
}